// Round 1
// 438.609 us; speedup vs baseline: 1.0116x; 1.0116x over previous
//
#include <hip/hip_runtime.h>
#include <cmath>

#define N_    8192
#define F_    256
#define G_    64
#define NPER_ 128
#define KK_   64
#define M_    4096   // G_*KK_
#define NZCAP 256    // P(Binom(8192,0.01) > 256) ~ 1e-50; mean 82, sd 9

typedef __attribute__((ext_vector_type(4))) float nf4;   // native float4 for builtins

// ---------------- K1: Xk = X @ kernel  (one wave per row) ----------------
__global__ __launch_bounds__(256) void k_xk(const float* __restrict__ X,
                                            const float* __restrict__ ker,
                                            float* __restrict__ Xk) {
    int wave = threadIdx.x >> 6, lane = threadIdx.x & 63;
    int row  = blockIdx.x * 4 + wave;
    const float4* xr = (const float4*)(X + (size_t)row * F_);
    const float4* kr = (const float4*)ker;
    float4 a = xr[lane], b = kr[lane];
    float v = a.x*b.x + a.y*b.y + a.z*b.z + a.w*b.w;
    for (int off = 32; off; off >>= 1) v += __shfl_down(v, off);
    if (lane == 0) Xk[row] = v;
}

// ---- K2: y = A @ Xk  AND  Afw = bitpack(A != 0)  (one wave per row) -----
// Bit layout per row: word w (0..127) = ballot of component e=w&3 at
// iter t=w>>2; bit l of word w  <->  column c = 256*(w>>2) + 4*l + (w&3).
__global__ __launch_bounds__(256) void k_y(const float* __restrict__ A,
                                           const float* __restrict__ Xk,
                                           float* __restrict__ y,
                                           unsigned long long* __restrict__ Afw) {
    int wave = threadIdx.x >> 6, lane = threadIdx.x & 63;
    int row  = blockIdx.x * 4 + wave;
    const nf4* ar = (const nf4*)(A + (size_t)row * N_);
    const float4* xr = (const float4*)Xk;
    unsigned long long* out = Afw + (size_t)row * 128;
    float v = 0.f;
#pragma unroll 4
    for (int t = 0; t < 32; ++t) {
        nf4 a = __builtin_nontemporal_load(&ar[lane + 64*t]);
        float4 b = xr[lane + 64*t];
        v += a.x*b.x + a.y*b.y + a.z*b.z + a.w*b.w;
        unsigned long long b0 = __ballot(a.x != 0.f);
        unsigned long long b1 = __ballot(a.y != 0.f);
        unsigned long long b2 = __ballot(a.z != 0.f);
        unsigned long long b3 = __ballot(a.w != 0.f);
        if (lane == 0) {
            out[t*4+0] = b0; out[t*4+1] = b1;
            out[t*4+2] = b2; out[t*4+3] = b3;
        }
    }
    for (int off = 32; off; off >>= 1) v += __shfl_down(v, off);
    if (lane == 0) y[row] = v;
}

// ---------------- K3: per-group top-64 selection -------------------------
// rank = #{u: s[u]>s[t]} + #{u<t: s[u]==s[t]}  (matches stable argsort)
// Also emits sel[c] = pooled position p with idx[p]==c, else 0xFFFF
// (per-group ascending == global ascending since groups are contiguous).
__global__ void k_select(const float* __restrict__ y,
                         int* __restrict__ idx,
                         unsigned short* __restrict__ selg) {
    __shared__ float s[NPER_];
    __shared__ unsigned char f[NPER_];
    int g = blockIdx.x, t = threadIdx.x;
    float my = y[g*NPER_ + t];
    s[t] = my;
    __syncthreads();
    int rank = 0;
#pragma unroll 8
    for (int u = 0; u < NPER_; ++u) {
        float su = s[u];
        rank += (su > my) || (su == my && u < t);
    }
    int sel = rank < KK_;
    f[t] = (unsigned char)sel;
    __syncthreads();
    int pos = 0;
    for (int u = 0; u < t; ++u) pos += f[u];
    if (sel) idx[g*KK_ + pos] = g*NPER_ + t;   // per-group ascending == global sort
    selg[g*NPER_ + t] = sel ? (unsigned short)(g*KK_ + pos)
                            : (unsigned short)0xFFFFu;
}

// ---- K4 (fused post-selection): three grid sections, 256 thr each -------
//   blocks [0,2048):    nz-lists, 2 selected rows per block
//   blocks [2048,3072): Ab bit-compaction, 8 k-rows per block (nz-driven)
//   blocks [3072,4096): X_pooled/I_pooled, 4 rows per block
__global__ __launch_bounds__(256) void k_post(const unsigned long long* __restrict__ Afw,
                                              const int* __restrict__ idx,
                                              const unsigned short* __restrict__ selg,
                                              const float* __restrict__ X,
                                              const float* __restrict__ y,
                                              const int* __restrict__ Iin,
                                              unsigned short* __restrict__ nzl,
                                              int* __restrict__ nzc,
                                              unsigned short* __restrict__ Ab,
                                              float* __restrict__ Xp,
                                              float* __restrict__ Ip) {
    __shared__ __align__(16) unsigned char smem[16384 + 2048 + 16];
    int b = blockIdx.x, t = threadIdx.x;

    if (b < 2048) {
        // ---- nz section: rows i = 2b, 2b+1 ----
        int* cnt2 = (int*)smem;
        int half = t >> 7, tw = t & 127;
        int i = b*2 + half;
        if (tw == 0) cnt2[half] = 0;
        __syncthreads();
        int r = idx[i];
        unsigned long long m = Afw[(size_t)r*128 + tw];
        int n = __popcll(m);
        int base = n ? atomicAdd(&cnt2[half], n) : 0;
        int tt = tw >> 2, e = tw & 3;
        while (m) {
            int l = __builtin_ctzll(m);
            m &= m - 1;
            int k = tt*256 + l*4 + e;
            if (base < NZCAP) nzl[(size_t)i*NZCAP + base] = (unsigned short)k;
            ++base;
        }
        __syncthreads();
        if (tw == 0) nzc[i] = cnt2[half] > NZCAP ? NZCAP : cnt2[half];
    } else if (b < 3072) {
        // ---- bitc section: k-rows [kbase, kbase+8), nz-driven scatter ----
        // Old code gathered all 4096 bits/row via 128 random-bank ds_read_b64
        // per thread (~8-way conflicts). New: decode the ~82 set bits of
        // Afw[k] (1% density), map column -> pooled position via sel[] LDS
        // table, atomicOr into a per-wave 4096-bit stage. ~50x less work.
        unsigned short* selL = (unsigned short*)smem;          // 16 KB
        unsigned* stg = (unsigned*)(smem + 16384);             // 4 waves * 512 B
        {
            const uint4* sg4 = (const uint4*)selg;
            uint4* sl4 = (uint4*)selL;
#pragma unroll
            for (int j = 0; j < 4; ++j) sl4[t + 256*j] = sg4[t + 256*j];
        }
        __syncthreads();
        int wave = t >> 6, lane = t & 63;
        unsigned* st = stg + wave*128;                 // this wave's 4096-bit row
        int k0 = (b - 2048)*8 + wave*2;                // 4 waves x 2 rows = 8 rows
        for (int r = 0; r < 2; ++r) {
            int k = k0 + r;
            const unsigned long long* rw = Afw + (size_t)k*128;
            unsigned long long m0 = rw[lane], m1 = rw[lane + 64];
            ((uint2*)st)[lane] = make_uint2(0u, 0u);   // zero stage (lockstep: ordered before atomics)
#pragma unroll
            for (int h = 0; h < 2; ++h) {
                unsigned long long m = h ? m1 : m0;
                int w = lane + h*64;
                int cb = ((w >> 2) << 8) | (w & 3);    // c = cb + 4*l
                while (m) {
                    int l = __builtin_ctzll(m);
                    m &= m - 1;
                    unsigned p = selL[cb + 4*l];
                    if (p != 0xFFFFu) atomicOr(&st[p >> 5], 1u << (p & 31));
                }
            }
            // intra-wave DS ops complete in program order -> stage is final here
            ((uint2*)(((unsigned*)Ab) + (size_t)k*128))[lane] = ((const uint2*)st)[lane];
        }
    } else {
        // ---- xpool section: rows i = 4*(b-3072) + wave ----
        int wave = t >> 6, lane = t & 63;
        int i = (b - 3072)*4 + wave;
        int src = idx[i];
        float tv = tanhf(y[src]);
        const float4* xr = (const float4*)(X + (size_t)src * F_);
        float4* op = (float4*)(Xp + (size_t)i * F_);
        float4 v = xr[lane];
        op[lane] = (float4){v.x*tv, v.y*tv, v.z*tv, v.w*tv};
        if (lane == 0) Ip[i] = (float)Iin[src];
    }
}

// ------ K5: sparse A_pooled: C[i][:] = sum_{k in nz(i)} Ab[k] bits -------
// Packed-byte accumulators: counts <= nnz(row) < 256, so u32 adds on 4x u8
// can never carry. Nibble->byte spread: (n * 0x204081) & 0x01010101.
__global__ __launch_bounds__(256) void k_spmm(const unsigned short* __restrict__ Ab,
                                              const unsigned short* __restrict__ nzl,
                                              const int* __restrict__ nzc,
                                              float* __restrict__ C) {
    __shared__ unsigned short ks[NZCAP];
    __shared__ int scnt;
    int i = blockIdx.x, t = threadIdx.x;       // t owns columns [16t, 16t+16)
    if (t == 0) scnt = nzc[i];
    if (t < NZCAP) ks[t] = nzl[(size_t)i*NZCAP + t];
    __syncthreads();
    int cnt = scnt;
    unsigned acc0 = 0, acc1 = 0, acc2 = 0, acc3 = 0;
    unsigned m0 = cnt > 0 ? (unsigned)Ab[(size_t)ks[0]*256 + t] : 0u;
    unsigned m1 = cnt > 1 ? (unsigned)Ab[(size_t)ks[1]*256 + t] : 0u;
    for (int q = 0; q < cnt; ++q) {
        unsigned mn = (q + 2 < cnt) ? (unsigned)Ab[(size_t)ks[q+2]*256 + t] : 0u;
        acc0 += ((m0        & 0xFu) * 0x204081u) & 0x01010101u;
        acc1 += (((m0 >> 4) & 0xFu) * 0x204081u) & 0x01010101u;
        acc2 += (((m0 >> 8) & 0xFu) * 0x204081u) & 0x01010101u;
        acc3 += ((m0 >> 12)         * 0x204081u) & 0x01010101u;
        m0 = m1; m1 = mn;
    }
    float4* cp = (float4*)(C + (size_t)i * M_ + t*16);
    unsigned a[4] = {acc0, acc1, acc2, acc3};
#pragma unroll
    for (int d = 0; d < 4; ++d)
        cp[d] = (float4){(float)(a[d] & 255u), (float)((a[d] >> 8) & 255u),
                         (float)((a[d] >> 16) & 255u), (float)(a[d] >> 24)};
}

extern "C" void kernel_launch(void* const* d_in, const int* in_sizes, int n_in,
                              void* d_out, int out_size, void* d_ws, size_t ws_size,
                              hipStream_t stream) {
    const float* X   = (const float*)d_in[0];
    const float* A   = (const float*)d_in[1];
    const int*   Iin = (const int*)d_in[2];
    const float* ker = (const float*)d_in[3];

    float* out = (float*)d_out;
    float* Xp = out;                                  // 4096*256
    float* Ap = out + (size_t)M_ * F_;                // 4096*4096
    float* Ip = Ap  + (size_t)M_ * M_;                // 4096

    char* ws = (char*)d_ws;
    unsigned long long* Afw = (unsigned long long*)ws;                 // 8 MB
    unsigned short* Ab  = (unsigned short*)(ws + (8u<<20));            // 4 MB
    unsigned short* nzl = (unsigned short*)(ws + (12u<<20));           // 2 MB
    char* tail = ws + (14u<<20);
    int*   nzc = (int*)  (tail);             // 16 KB
    float* Xk  = (float*)(tail + 32768);
    float* yv  = (float*)(tail + 65536);
    int*   idx = (int*)  (tail + 98304);     // 16 KB
    unsigned short* selp = (unsigned short*)(tail + 131072);  // 16 KB

    k_xk    <<<N_/4, 256, 0, stream>>>(X, ker, Xk);
    k_y     <<<N_/4, 256, 0, stream>>>(A, Xk, yv, Afw);
    k_select<<<G_,   128, 0, stream>>>(yv, idx, selp);
    k_post  <<<4096, 256, 0, stream>>>(Afw, idx, selp, X, yv, Iin, nzl, nzc, Ab, Xp, Ip);
    k_spmm  <<<M_,   256, 0, stream>>>(Ab, nzl, nzc, Ap);
}

// Round 2
// 419.142 us; speedup vs baseline: 1.0585x; 1.0464x over previous
//
#include <hip/hip_runtime.h>
#include <cmath>

#define N_    8192
#define F_    256
#define G_    64
#define NPER_ 128
#define KK_   64
#define M_    4096   // G_*KK_
#define NZCAP 256    // P(Binom(8192,0.01) > 256) ~ 1e-50; mean 82, sd 9

typedef __attribute__((ext_vector_type(4))) float nf4;   // native float4 for builtins

// ---------------- K1: Xk = X @ kernel  (one wave per row) ----------------
__global__ __launch_bounds__(256) void k_xk(const float* __restrict__ X,
                                            const float* __restrict__ ker,
                                            float* __restrict__ Xk) {
    int wave = threadIdx.x >> 6, lane = threadIdx.x & 63;
    int row  = blockIdx.x * 4 + wave;
    const float4* xr = (const float4*)(X + (size_t)row * F_);
    const float4* kr = (const float4*)ker;
    float4 a = xr[lane], b = kr[lane];
    float v = a.x*b.x + a.y*b.y + a.z*b.z + a.w*b.w;
    for (int off = 32; off; off >>= 1) v += __shfl_down(v, off);
    if (lane == 0) Xk[row] = v;
}

// ---- K2: y = A @ Xk  AND  Afw = bitpack(A != 0)  (one wave per row) -----
// Bit layout per row: word w (0..127) = ballot of component e=w&3 at
// iter t=w>>2; bit l of word w  <->  column c = 256*(w>>2) + 4*l + (w&3).
__global__ __launch_bounds__(256) void k_y(const float* __restrict__ A,
                                           const float* __restrict__ Xk,
                                           float* __restrict__ y,
                                           unsigned long long* __restrict__ Afw) {
    int wave = threadIdx.x >> 6, lane = threadIdx.x & 63;
    int row  = blockIdx.x * 4 + wave;
    const nf4* ar = (const nf4*)(A + (size_t)row * N_);
    const float4* xr = (const float4*)Xk;
    unsigned long long* out = Afw + (size_t)row * 128;
    float v = 0.f;
#pragma unroll 4
    for (int t = 0; t < 32; ++t) {
        nf4 a = __builtin_nontemporal_load(&ar[lane + 64*t]);
        float4 b = xr[lane + 64*t];
        v += a.x*b.x + a.y*b.y + a.z*b.z + a.w*b.w;
        unsigned long long b0 = __ballot(a.x != 0.f);
        unsigned long long b1 = __ballot(a.y != 0.f);
        unsigned long long b2 = __ballot(a.z != 0.f);
        unsigned long long b3 = __ballot(a.w != 0.f);
        if (lane == 0) {
            out[t*4+0] = b0; out[t*4+1] = b1;
            out[t*4+2] = b2; out[t*4+3] = b3;
        }
    }
    for (int off = 32; off; off >>= 1) v += __shfl_down(v, off);
    if (lane == 0) y[row] = v;
}

// ---------------- K3: per-group top-64 selection -------------------------
// rank = #{u: s[u]>s[t]} + #{u<t: s[u]==s[t]}  (matches stable argsort)
// Also emits sel[c] = pooled position p with idx[p]==c, else 0xFFFF.
__global__ void k_select(const float* __restrict__ y,
                         int* __restrict__ idx,
                         unsigned short* __restrict__ selg) {
    __shared__ float s[NPER_];
    __shared__ unsigned char f[NPER_];
    int g = blockIdx.x, t = threadIdx.x;
    float my = y[g*NPER_ + t];
    s[t] = my;
    __syncthreads();
    int rank = 0;
#pragma unroll 8
    for (int u = 0; u < NPER_; ++u) {
        float su = s[u];
        rank += (su > my) || (su == my && u < t);
    }
    int sel = rank < KK_;
    f[t] = (unsigned char)sel;
    __syncthreads();
    int pos = 0;
    for (int u = 0; u < t; ++u) pos += f[u];
    if (sel) idx[g*KK_ + pos] = g*NPER_ + t;   // per-group ascending == global sort
    selg[g*NPER_ + t] = sel ? (unsigned short)(g*KK_ + pos)
                            : (unsigned short)0xFFFFu;
}

// ---- K4: Ab bit-compaction, nz-driven scatter. 8 k-rows per block. ------
// Decode the ~82 set bits of Afw[k] (1% density), map column -> pooled
// position via sel[] LDS table, atomicOr into a per-wave 4096-bit stage.
__global__ __launch_bounds__(256) void k_bitc(const unsigned long long* __restrict__ Afw,
                                              const unsigned short* __restrict__ selg,
                                              unsigned short* __restrict__ Ab) {
    __shared__ __align__(16) unsigned char smem[16384 + 2048 + 16];
    int b = blockIdx.x, t = threadIdx.x;
    unsigned short* selL = (unsigned short*)smem;          // 16 KB
    unsigned* stg = (unsigned*)(smem + 16384);             // 4 waves * 512 B
    {
        const uint4* sg4 = (const uint4*)selg;
        uint4* sl4 = (uint4*)selL;
#pragma unroll
        for (int j = 0; j < 4; ++j) sl4[t + 256*j] = sg4[t + 256*j];
    }
    __syncthreads();
    int wave = t >> 6, lane = t & 63;
    unsigned* st = stg + wave*128;                 // this wave's 4096-bit row
    int k0 = b*8 + wave*2;                         // 4 waves x 2 rows = 8 rows
    for (int r = 0; r < 2; ++r) {
        int k = k0 + r;
        const unsigned long long* rw = Afw + (size_t)k*128;
        unsigned long long m0 = rw[lane], m1 = rw[lane + 64];
        ((uint2*)st)[lane] = make_uint2(0u, 0u);   // zero stage (lockstep: ordered before atomics)
#pragma unroll
        for (int h = 0; h < 2; ++h) {
            unsigned long long m = h ? m1 : m0;
            int w = lane + h*64;
            int cb = ((w >> 2) << 8) | (w & 3);    // c = cb + 4*l
            while (m) {
                int l = __builtin_ctzll(m);
                m &= m - 1;
                unsigned p = selL[cb + 4*l];
                if (p != 0xFFFFu) atomicOr(&st[p >> 5], 1u << (p & 31));
            }
        }
        // intra-wave DS ops complete in program order -> stage is final here
        ((uint2*)(((unsigned*)Ab) + (size_t)k*128))[lane] = ((const uint2*)st)[lane];
    }
}

// ---- K5 (fused pool): 2 output rows per block, 256 threads --------------
// Per row i = 2b+half (half = t>>7, 128 threads each):
//   1. decode nz list of Afw[idx[i]] into LDS (order-irrelevant for a sum)
//   2. xpool: Xp[i] = X[idx[i]] * tanh(y[idx[i]]), Ip[i]
//   3. CSA bit-plane accumulate: thread tw owns 32 cols (u32 of Ab row);
//      8 planes p0..p7 hold per-column counts < 256. Two masks per step:
//      half-add (s,c) then ripple -> ~20 VALU per pair per 32 cols vs 32
//      for the nibble-spread method. Final plane->byte expansion once.
__global__ __launch_bounds__(256) void k_pool(const unsigned long long* __restrict__ Afw,
                                              const int* __restrict__ idx,
                                              const unsigned short* __restrict__ Ab,
                                              const float* __restrict__ X,
                                              const float* __restrict__ y,
                                              const int* __restrict__ Iin,
                                              float* __restrict__ C,
                                              float* __restrict__ Xp,
                                              float* __restrict__ Ip) {
    __shared__ unsigned short ls[2][NZCAP];
    __shared__ int cnts[2];
    int b = blockIdx.x, t = threadIdx.x;
    int half = t >> 7, tw = t & 127;
    int i = b*2 + half;
    int src = idx[i];
    if (tw == 0) cnts[half] = 0;
    __syncthreads();
    // ---- decode Afw row -> LDS list (unordered) ----
    {
        unsigned long long m = Afw[(size_t)src*128 + tw];
        int n = __popcll(m);
        int base = n ? atomicAdd(&cnts[half], n) : 0;
        int tt = tw >> 2, e = tw & 3;
        while (m) {
            int l = __builtin_ctzll(m);
            m &= m - 1;
            int k = tt*256 + l*4 + e;
            if (base < NZCAP) ls[half][base] = (unsigned short)k;
            ++base;
        }
    }
    // ---- xpool (wave 0 of each half) ----
    if (tw < 64) {
        float tv = tanhf(y[src]);
        const float4* xr = (const float4*)(X + (size_t)src * F_);
        float4 v = xr[tw];
        ((float4*)(Xp + (size_t)i * F_))[tw] = (float4){v.x*tv, v.y*tv, v.z*tv, v.w*tv};
        if (tw == 0) Ip[i] = (float)Iin[src];
    }
    __syncthreads();
    int cnt = cnts[half];
    if (cnt > NZCAP) cnt = NZCAP;
    // ---- CSA accumulate ----
    const unsigned* Abu = (const unsigned*)Ab;
    unsigned p0=0,p1=0,p2=0,p3=0,p4=0,p5=0,p6=0,p7=0;
    unsigned a0 = cnt > 0 ? Abu[(size_t)ls[half][0]*128 + tw] : 0u;
    unsigned a1 = cnt > 1 ? Abu[(size_t)ls[half][1]*128 + tw] : 0u;
    for (int q = 0; q < cnt; q += 2) {
        unsigned n0 = (q+2 < cnt) ? Abu[(size_t)ls[half][q+2]*128 + tw] : 0u;
        unsigned n1 = (q+3 < cnt) ? Abu[(size_t)ls[half][q+3]*128 + tw] : 0u;
        unsigned s  = a0 ^ a1, c = a0 & a1;      // half-add two masks
        unsigned x  = p0 ^ s,  cy = p0 & s;  p0 = x;
        unsigned t1 = p1 ^ c;                    // full-add c+cy into p1
        x = t1 ^ cy;
        unsigned cy1 = (p1 & c) | (t1 & cy);
        p1 = x;
        x = p2 ^ cy1; cy1 = p2 & cy1; p2 = x;    // ripple
        x = p3 ^ cy1; cy1 = p3 & cy1; p3 = x;
        x = p4 ^ cy1; cy1 = p4 & cy1; p4 = x;
        x = p5 ^ cy1; cy1 = p5 & cy1; p5 = x;
        x = p6 ^ cy1; cy1 = p6 & cy1; p6 = x;
        p7 ^= cy1;
        a0 = n0; a1 = n1;
    }
    // ---- expand planes -> byte counts -> floats ----
    unsigned acc[8] = {0,0,0,0,0,0,0,0};
    unsigned pl[8] = {p0,p1,p2,p3,p4,p5,p6,p7};
#pragma unroll
    for (int bb = 0; bb < 8; ++bb) {
        unsigned p = pl[bb];
#pragma unroll
        for (int g = 0; g < 8; ++g)
            acc[g] += ((((p >> (4*g)) & 0xFu) * 0x204081u) & 0x01010101u) << bb;
    }
    float4* cp = (float4*)(C + (size_t)i * M_ + tw*32);
#pragma unroll
    for (int g = 0; g < 8; ++g)
        cp[g] = (float4){(float)(acc[g] & 255u), (float)((acc[g] >> 8) & 255u),
                         (float)((acc[g] >> 16) & 255u), (float)(acc[g] >> 24)};
}

extern "C" void kernel_launch(void* const* d_in, const int* in_sizes, int n_in,
                              void* d_out, int out_size, void* d_ws, size_t ws_size,
                              hipStream_t stream) {
    const float* X   = (const float*)d_in[0];
    const float* A   = (const float*)d_in[1];
    const int*   Iin = (const int*)d_in[2];
    const float* ker = (const float*)d_in[3];

    float* out = (float*)d_out;
    float* Xp = out;                                  // 4096*256
    float* Ap = out + (size_t)M_ * F_;                // 4096*4096
    float* Ip = Ap  + (size_t)M_ * M_;                // 4096

    char* ws = (char*)d_ws;
    unsigned long long* Afw = (unsigned long long*)ws;                 // 8 MB
    unsigned short* Ab  = (unsigned short*)(ws + (8u<<20));            // 4 MB
    char* tail = ws + (14u<<20);
    float* Xk  = (float*)(tail + 32768);
    float* yv  = (float*)(tail + 65536);
    int*   idx = (int*)  (tail + 98304);     // 16 KB
    unsigned short* selp = (unsigned short*)(tail + 131072);  // 16 KB

    k_xk    <<<N_/4,   256, 0, stream>>>(X, ker, Xk);
    k_y     <<<N_/4,   256, 0, stream>>>(A, Xk, yv, Afw);
    k_select<<<G_,     128, 0, stream>>>(yv, idx, selp);
    k_bitc  <<<N_/8,   256, 0, stream>>>(Afw, selp, Ab);
    k_pool  <<<M_/2,   256, 0, stream>>>(Afw, idx, Ab, X, yv, Iin, Ap, Xp, Ip);
}